// Round 9
// baseline (411.120 us; speedup 1.0000x reference)
//
#include <hip/hip_runtime.h>
#include <hip/hip_cooperative_groups.h>
#include <math.h>

namespace cg = cooperative_groups;

typedef __bf16 bf16_t;
typedef bf16_t bf16x4 __attribute__((ext_vector_type(4)));
typedef bf16_t bf16x8 __attribute__((ext_vector_type(8)));
typedef float  f32x4  __attribute__((ext_vector_type(4)));

__device__ __forceinline__ float softplus_f(float x) {
    return (x > 20.f) ? x : log1pf(expf(x));
}

__device__ __forceinline__ float fast_rcp(float x) {
#if __has_builtin(__builtin_amdgcn_rcpf)
    return __builtin_amdgcn_rcpf(x);
#else
    return 1.0f / x;
#endif
}

// LDS layout (phase-aliased)
#define OFF_VM   0
#define OFF_VV   36864
#define OFF_FS   73728
#define OFF_SC   82176
#define OFF_PHI  98816
#define OFF_PLO  107264
#define OFF_P2H  115712
#define OFF_P2L  124160
#define SMEM_SZ  133632   // 132608 attn + 1024 spare (feat red)

struct MegaArgs {
    const float* wsrc[8];
    const float* mu; const float* var;
    const bf16_t* A[8];
    const bf16_t* Wt[8];
    const float*  bias[8];
    float*        dst[8];
    int           splus[8];
    bf16_t* Abf_mu; bf16_t* Abf_var;
    bf16_t* WtB;
    float*  Proj;
    bf16_t* Obf_mu; bf16_t* Obf_var;
    bf16_t* Gbf; float* cvec;
};

// ---------------- phase A: weights transpose+convert + act convert ----------------
__device__ void prep_phase(const MegaArgs& a, unsigned char* smem, int bid, int t) {
    {   // act convert: one 8-float unit per thread (256 blocks x 256 thr = 65536 units)
        const int gid = bid * 256 + t;
        const float* s; bf16_t* d; int off;
        if (gid < 32768) { s = a.mu;  d = a.Abf_mu;  off = gid * 8; }
        else             { s = a.var; d = a.Abf_var; off = (gid - 32768) * 8; }
        float4 v0 = *(const float4*)(s + off);
        float4 v1 = *(const float4*)(s + off + 4);
        bf16x8 o;
        o[0] = (bf16_t)v0.x; o[1] = (bf16_t)v0.y; o[2] = (bf16_t)v0.z; o[3] = (bf16_t)v0.w;
        o[4] = (bf16_t)v1.x; o[5] = (bf16_t)v1.y; o[6] = (bf16_t)v1.z; o[7] = (bf16_t)v1.w;
        *(bf16x8*)(d + off) = o;
    }
    bf16_t (*Ts)[72] = (bf16_t(*)[72])smem;
    const int r0 = t >> 4, c4 = (t & 15) * 4;
#pragma unroll 1
    for (int rep = 0; rep < 8; ++rep) {
        const int tile = bid + rep * 256;          // 0..2047
        const int wm = tile >> 8, kt = (tile >> 4) & 15, nt = tile & 15;
        const float* __restrict__ W = a.wsrc[wm];
        bf16_t* __restrict__ Wt = a.WtB + (size_t)wm * 1048576;
#pragma unroll
        for (int rr = 0; rr < 4; ++rr) {
            const int r = r0 + rr * 16;
            const float4 v = *(const float4*)&W[(size_t)(kt * 64 + r) * 1024 + nt * 64 + c4];
            Ts[c4 + 0][r] = (bf16_t)v.x;
            Ts[c4 + 1][r] = (bf16_t)v.y;
            Ts[c4 + 2][r] = (bf16_t)v.z;
            Ts[c4 + 3][r] = (bf16_t)v.w;
        }
        __syncthreads();
#pragma unroll
        for (int rr = 0; rr < 2; ++rr) {
            const int chunk = t + rr * 256;
            const int n = chunk >> 3, kc = (chunk & 7) * 8;
            bf16x8 v = *(const bf16x8*)&Ts[n][kc];
            *(bf16x8*)&Wt[(size_t)(nt * 64 + n) * 1024 + kt * 64 + kc] = v;
        }
        __syncthreads();   // WAR: Ts reused next rep
    }
}

// ---------------- gemm tile (R5/R8-verified body, 64x64 split-K) ----------------
__device__ void gemm_tile(const MegaArgs& a, int z, int n_base, int m_base,
                          unsigned char* smem, int t) {
    const bf16_t* __restrict__ A    = a.A[z];
    const bf16_t* __restrict__ Wt   = a.Wt[z];
    const float*  __restrict__ bias = a.bias[z];
    float*        __restrict__ dst  = a.dst[z];
    const int sp = a.splus[z];

    bf16_t* stage = (bf16_t*)smem;
    float*  Cr    = (float*)smem;

    const int lane = t & 63;
    const int w = t >> 6;
    bf16_t* As = stage + w * 9216;
    bf16_t* Bs = As + 4608;

    const int r8 = lane >> 3, kb = lane & 7;
    const int fr = lane & 15, fq = lane >> 4, fk = fq * 8;

    f32x4 acc[4][4] = {};

#pragma unroll
    for (int s = 0; s < 4; ++s) {
        const int k0 = w * 256 + s * 64;
#pragma unroll
        for (int i = 0; i < 8; ++i) {
            const int row = i * 8 + r8;
            bf16x8 av = *(const bf16x8*)&A [(size_t)(m_base + row) * 1024 + k0 + kb * 8];
            bf16x8 bv = *(const bf16x8*)&Wt[(size_t)(n_base + row) * 1024 + k0 + kb * 8];
            *(bf16x8*)&As[row * 72 + kb * 8] = av;
            *(bf16x8*)&Bs[row * 72 + kb * 8] = bv;
        }
#pragma unroll
        for (int kh = 0; kh < 2; ++kh) {
            bf16x8 aF[4], bF[4];
#pragma unroll
            for (int i = 0; i < 4; ++i)
                aF[i] = *(const bf16x8*)&As[(i * 16 + fr) * 72 + kh * 32 + fk];
#pragma unroll
            for (int j = 0; j < 4; ++j)
                bF[j] = *(const bf16x8*)&Bs[(j * 16 + fr) * 72 + kh * 32 + fk];
#pragma unroll
            for (int i = 0; i < 4; ++i)
#pragma unroll
                for (int j = 0; j < 4; ++j)
                    acc[i][j] = __builtin_amdgcn_mfma_f32_16x16x32_bf16(aF[i], bF[j], acc[i][j], 0, 0, 0);
        }
    }

    __syncthreads();
    {
        float* Crw = Cr + w * 4352;
        const int orow = fq * 4;
#pragma unroll
        for (int i = 0; i < 4; ++i)
#pragma unroll
            for (int j = 0; j < 4; ++j)
#pragma unroll
                for (int rr = 0; rr < 4; ++rr)
                    Crw[(i * 16 + orow + rr) * 68 + j * 16 + fr] = acc[i][j][rr];
    }
    __syncthreads();

    const int cc = (t & 15) * 4;
    f32x4 bv4 = *(const f32x4*)&bias[n_base + cc];
#pragma unroll
    for (int i = 0; i < 4; ++i) {
        const int row = (t >> 4) + i * 16;
        f32x4 s0 = *(const f32x4*)&Cr[0 * 4352 + row * 68 + cc];
        f32x4 s1 = *(const f32x4*)&Cr[1 * 4352 + row * 68 + cc];
        f32x4 s2 = *(const f32x4*)&Cr[2 * 4352 + row * 68 + cc];
        f32x4 s3 = *(const f32x4*)&Cr[3 * 4352 + row * 68 + cc];
        f32x4 v = (s0 + s1) + (s2 + s3) + bv4;
        if (sp) {
            v[0] = softplus_f(v[0]); v[1] = softplus_f(v[1]);
            v[2] = softplus_f(v[2]); v[3] = softplus_f(v[3]);
        }
        *(f32x4*)&dst[(size_t)(m_base + row) * 1024 + n_base + cc] = v;
    }
    __syncthreads();   // WAR: Cr aliased by next tile's staging
}

// ---------------- feat body (64 units: h, kb) ----------------
__device__ void feat_body(const MegaArgs& a, int h, int kb, int t, unsigned char* smem) {
    const float* Km = a.Proj + 2 * 262144;
    const float* Kv = a.Proj + 3 * 262144;
    const int kx = t & 63;
    const int dg = t >> 6;
    const int katt = kb * 64 + kx;
    const float* kvp = Kv + (size_t)katt * 1024 + h * 64 + dg * 16;
    const float* kmp = Km + (size_t)katt * 1024 + h * 64 + dg * 16;
    bf16_t* grow = a.Gbf + ((size_t)(h * 256 + katt)) * 128;
    float cp = 0.f;
#pragma unroll
    for (int c = 0; c < 4; ++c) {
        f32x4 kv = *(const f32x4*)(kvp + c * 4);
        f32x4 km = *(const f32x4*)(kmp + c * 4);
        bf16x4 o1, o2;
#pragma unroll
        for (int e = 0; e < 4; ++e) {
            const float r = 0.5f * fast_rcp(kv[e]);
            o1[e] = (bf16_t)r;
            o2[e] = (bf16_t)(-2.f * km[e] * r);
            cp += km[e] * km[e] * r + 0.5f * __logf(kv[e]);
        }
        *(bf16x4*)&grow[dg * 16 + c * 4]      = o1;
        *(bf16x4*)&grow[64 + dg * 16 + c * 4] = o2;
    }
    float* red = (float*)(smem + 132608);   // 4x64 f32
    red[dg * 64 + kx] = cp;
    __syncthreads();
    if (dg == 0)
        a.cvec[h * 256 + katt] = red[0 * 64 + kx] + red[1 * 64 + kx] + red[2 * 64 + kx] + red[3 * 64 + kx];
}

// ---------------- attn body (R8-verified attn_v6) ----------------
__device__ void attn_body(const MegaArgs& a, int qt, int h, int t, unsigned char* smem) {
    const float* Qm = a.Proj;
    const float* Qv = a.Proj + 262144;
    const float* Vm = a.Proj + 4 * 262144;
    const float* Vv = a.Proj + 5 * 262144;
    const bf16_t* Gbf = a.Gbf;

    bf16_t* Vsm = (bf16_t*)(smem + OFF_VM);
    bf16_t* Vsv = (bf16_t*)(smem + OFF_VV);
    float*  Fs  = (float*)(smem + OFF_FS);
    float*  Sc  = (float*)(smem + OFF_SC);
    bf16_t* Phi = (bf16_t*)(smem + OFF_PHI);
    bf16_t* Plo = (bf16_t*)(smem + OFF_PLO);
    bf16_t* P2h = (bf16_t*)(smem + OFF_P2H);
    bf16_t* P2l = (bf16_t*)(smem + OFF_P2L);

    const int w = t >> 6, lane = t & 63;
    const int fr = lane & 15, fq = lane >> 4;
    const int n0 = w * 64;

    const bf16_t* gB = Gbf + ((size_t)(h * 256 + n0 + fr)) * 128 + fq * 8;

    bf16x8 bcur[4];
#pragma unroll
    for (int ks = 0; ks < 4; ++ks) bcur[ks] = *(const bf16x8*)(gB + ks * 32);

    {
        const int r = t >> 4, c = t & 15;
        f32x4 qm = *(const f32x4*)(Qm + (size_t)(qt * 16 + r) * 1024 + h * 64 + c * 4);
        f32x4 qv = *(const f32x4*)(Qv + (size_t)(qt * 16 + r) * 1024 + h * 64 + c * 4);
        *(f32x4*)&Fs[r * 132 + c * 4]      = qm * qm + qv;
        *(f32x4*)&Fs[r * 132 + 64 + c * 4] = qm;
    }
    __syncthreads();

    bf16x8 ahi[4], alo[4];
#pragma unroll
    for (int ks = 0; ks < 4; ++ks) {
        f32x4 f0 = *(const f32x4*)&Fs[fr * 132 + ks * 32 + fq * 8];
        f32x4 f1 = *(const f32x4*)&Fs[fr * 132 + ks * 32 + fq * 8 + 4];
#pragma unroll
        for (int e = 0; e < 4; ++e) {
            bf16_t hb = (bf16_t)f0[e];
            ahi[ks][e] = hb; alo[ks][e] = (bf16_t)(f0[e] - (float)hb);
            bf16_t hb2 = (bf16_t)f1[e];
            ahi[ks][e + 4] = hb2; alo[ks][e + 4] = (bf16_t)(f1[e] - (float)hb2);
        }
    }

    const int vk = t >> 2, vpart = t & 3;
#pragma unroll
    for (int nt = 0; nt < 4; ++nt) {
        const int ua = 2 * nt, ub = 2 * nt + 1;
        const float* vsa = ((ua >> 2) ? Vv : Vm) + (size_t)(vk + (ua & 3) * 64) * 1024 + h * 64 + vpart * 16;
        const float* vsb = ((ub >> 2) ? Vv : Vm) + (size_t)(vk + (ub & 3) * 64) * 1024 + h * 64 + vpart * 16;
        f32x4 va0 = *(const f32x4*)(vsa),     va1 = *(const f32x4*)(vsa + 4);
        f32x4 va2 = *(const f32x4*)(vsa + 8), va3 = *(const f32x4*)(vsa + 12);
        f32x4 vb0 = *(const f32x4*)(vsb),     vb1 = *(const f32x4*)(vsb + 4);
        f32x4 vb2 = *(const f32x4*)(vsb + 8), vb3 = *(const f32x4*)(vsb + 12);

        bf16x8 bnxt[4];
        if (nt < 3) {
#pragma unroll
            for (int ks = 0; ks < 4; ++ks)
                bnxt[ks] = *(const bf16x8*)(gB + (size_t)(nt + 1) * 2048 + ks * 32);
        }

        f32x4 acc = {0.f, 0.f, 0.f, 0.f};
#pragma unroll
        for (int ks = 0; ks < 4; ++ks) {
            acc = __builtin_amdgcn_mfma_f32_16x16x32_bf16(ahi[ks], bcur[ks], acc, 0, 0, 0);
            acc = __builtin_amdgcn_mfma_f32_16x16x32_bf16(alo[ks], bcur[ks], acc, 0, 0, 0);
        }

        {
            bf16_t* da = ((ua >> 2) ? Vsv : Vsm) + (vk + (ua & 3) * 64) * 72 + vpart * 16;
            bf16_t* db = ((ub >> 2) ? Vsv : Vsm) + (vk + (ub & 3) * 64) * 72 + vpart * 16;
            bf16x8 o0, o1;
            o0[0]=(bf16_t)va0[0]; o0[1]=(bf16_t)va0[1]; o0[2]=(bf16_t)va0[2]; o0[3]=(bf16_t)va0[3];
            o0[4]=(bf16_t)va1[0]; o0[5]=(bf16_t)va1[1]; o0[6]=(bf16_t)va1[2]; o0[7]=(bf16_t)va1[3];
            o1[0]=(bf16_t)va2[0]; o1[1]=(bf16_t)va2[1]; o1[2]=(bf16_t)va2[2]; o1[3]=(bf16_t)va2[3];
            o1[4]=(bf16_t)va3[0]; o1[5]=(bf16_t)va3[1]; o1[6]=(bf16_t)va3[2]; o1[7]=(bf16_t)va3[3];
            *(bf16x8*)(da)     = o0;
            *(bf16x8*)(da + 8) = o1;
            o0[0]=(bf16_t)vb0[0]; o0[1]=(bf16_t)vb0[1]; o0[2]=(bf16_t)vb0[2]; o0[3]=(bf16_t)vb0[3];
            o0[4]=(bf16_t)vb1[0]; o0[5]=(bf16_t)vb1[1]; o0[6]=(bf16_t)vb1[2]; o0[7]=(bf16_t)vb1[3];
            o1[0]=(bf16_t)vb2[0]; o1[1]=(bf16_t)vb2[1]; o1[2]=(bf16_t)vb2[2]; o1[3]=(bf16_t)vb2[3];
            o1[4]=(bf16_t)vb3[0]; o1[5]=(bf16_t)vb3[1]; o1[6]=(bf16_t)vb3[2]; o1[7]=(bf16_t)vb3[3];
            *(bf16x8*)(db)     = o0;
            *(bf16x8*)(db + 8) = o1;
        }

        const float cv = a.cvec[h * 256 + n0 + nt * 16 + fr];
        f32x4 lg = (acc + cv) * (-0.125f);
#pragma unroll
        for (int reg = 0; reg < 4; ++reg)
            Sc[(fq * 4 + reg) * 260 + n0 + nt * 16 + fr] = lg[reg];

#pragma unroll
        for (int ks = 0; ks < 4; ++ks) bcur[ks] = bnxt[ks];
    }
    __syncthreads();

    const int fw = w * 4;
    f32x4 sr[4];
#pragma unroll
    for (int r = 0; r < 4; ++r)
        sr[r] = *(const f32x4*)&Sc[(fw + r) * 260 + lane * 4];
#pragma unroll
    for (int r = 0; r < 4; ++r) {
        f32x4 s = sr[r];
        float mloc = fmaxf(fmaxf(s[0], s[1]), fmaxf(s[2], s[3]));
#pragma unroll
        for (int off = 32; off > 0; off >>= 1)
            mloc = fmaxf(mloc, __shfl_xor(mloc, off, 64));
        s[0] = __expf(s[0] - mloc); s[1] = __expf(s[1] - mloc);
        s[2] = __expf(s[2] - mloc); s[3] = __expf(s[3] - mloc);
        float sl = (s[0] + s[1]) + (s[2] + s[3]);
#pragma unroll
        for (int off = 32; off > 0; off >>= 1)
            sl += __shfl_xor(sl, off, 64);
        sr[r] = s * fast_rcp(sl);
    }

#pragma unroll
    for (int r = 0; r < 4; ++r) {
        bf16x4 phi, plo, p2hi, p2lo;
#pragma unroll
        for (int e = 0; e < 4; ++e) {
            const float p = sr[r][e];
            const bf16_t hb = (bf16_t)p;
            phi[e] = hb; plo[e] = (bf16_t)(p - (float)hb);
            const float p2 = p * p;
            const bf16_t h2 = (bf16_t)p2;
            p2hi[e] = h2; p2lo[e] = (bf16_t)(p2 - (float)h2);
        }
        const int row = fw + r;
        *(bf16x4*)&Phi[row * 264 + lane * 4] = phi;
        *(bf16x4*)&Plo[row * 264 + lane * 4] = plo;
        *(bf16x4*)&P2h[row * 264 + lane * 4] = p2hi;
        *(bf16x4*)&P2l[row * 264 + lane * 4] = p2lo;
    }
    __syncthreads();

    f32x4 accm = {0.f,0.f,0.f,0.f}, accv = {0.f,0.f,0.f,0.f};
#pragma unroll
    for (int k0 = 0; k0 < 256; k0 += 32) {
        const int ka = k0 + fq * 8;
        bf16x8 ahi2 = *(const bf16x8*)&Phi[fr * 264 + ka];
        bf16x8 alo2 = *(const bf16x8*)&Plo[fr * 264 + ka];
        bf16x8 a2h  = *(const bf16x8*)&P2h[fr * 264 + ka];
        bf16x8 a2l  = *(const bf16x8*)&P2l[fr * 264 + ka];
        bf16x8 bm, bv;
#pragma unroll
        for (int j = 0; j < 8; ++j) {
            const int kk = ka + j;
            bm[j] = Vsm[kk * 72 + w * 16 + fr];
            bv[j] = Vsv[kk * 72 + w * 16 + fr];
        }
        accm = __builtin_amdgcn_mfma_f32_16x16x32_bf16(ahi2, bm, accm, 0, 0, 0);
        accm = __builtin_amdgcn_mfma_f32_16x16x32_bf16(alo2, bm, accm, 0, 0, 0);
        accv = __builtin_amdgcn_mfma_f32_16x16x32_bf16(a2h,  bv, accv, 0, 0, 0);
        accv = __builtin_amdgcn_mfma_f32_16x16x32_bf16(a2l,  bv, accv, 0, 0, 0);
    }

#pragma unroll
    for (int reg = 0; reg < 4; ++reg) {
        const int qg = qt * 16 + fq * 4 + reg;
        const size_t ob = (size_t)qg * 1024 + h * 64 + w * 16 + fr;
        a.Obf_mu[ob]  = (bf16_t)accm[reg];
        a.Obf_var[ob] = (bf16_t)accv[reg];
    }
    __syncthreads();   // LDS quiesced before next phase reuses it
}

// ---------------- mega kernel ----------------
__global__ __launch_bounds__(256, 1) void mega_kernel(MegaArgs a) {
    __shared__ __align__(16) unsigned char smem[SMEM_SZ];
    cg::grid_group grid = cg::this_grid();
    const int bid = blockIdx.x;
    const int t = threadIdx.x;

    // A: prep
    prep_phase(a, smem, bid, t);
    __threadfence();
    grid.sync();

    // C: projection gemms (384 tiles)
#pragma unroll 1
    for (int tt = bid; tt < 384; tt += 256) {
        const int z = tt / 64, rem = tt % 64;
        gemm_tile(a, z, (rem & 15) * 64, (rem >> 4) * 64, smem, t);
    }
    __threadfence();
    grid.sync();

    // E: feat (64 units)
    if (bid < 64) feat_body(a, bid >> 2, bid & 3, t, smem);
    __threadfence();
    grid.sync();

    // G: attn (256 blocks)
    attn_body(a, bid & 15, bid >> 4, t, smem);
    __threadfence();
    grid.sync();

    // I: output gemms (128 tiles)
    if (bid < 128) {
        const int z = 6 + bid / 64, rem = bid % 64;
        gemm_tile(a, z, (rem & 15) * 64, (rem >> 4) * 64, smem, t);
    }
}

// ---------------- launch ----------------
extern "C" void kernel_launch(void* const* d_in, const int* in_sizes, int n_in,
                              void* d_out, int out_size, void* d_ws, size_t ws_size,
                              hipStream_t stream) {
    uint8_t* ws = (uint8_t*)d_ws;
    bf16_t* Abf_mu  = (bf16_t*)(ws);
    bf16_t* Abf_var = (bf16_t*)(ws + (512u << 10));
    bf16_t* WtB     = (bf16_t*)(ws + (1u << 20));
    float*  Proj    = (float*)(ws + (17u << 20));
    bf16_t* Obf_mu  = (bf16_t*)(ws + (23u << 20));
    bf16_t* Obf_var = (bf16_t*)(ws + (23u << 20) + (512u << 10));
    bf16_t* Gbf     = (bf16_t*)(ws + (24u << 20));
    float*  cvec    = (float*)(ws + (25u << 20));

    MegaArgs ma;
    for (int i = 0; i < 8; ++i) ma.wsrc[i] = (const float*)d_in[2 + 2 * i];
    ma.mu = (const float*)d_in[0];
    ma.var = (const float*)d_in[1];
    for (int z = 0; z < 6; ++z) {
        ma.A[z]    = (z & 1) ? Abf_var : Abf_mu;
        ma.Wt[z]   = WtB + (size_t)z * 1048576;
        ma.bias[z] = (const float*)d_in[3 + 2 * z];
        ma.dst[z]  = Proj + (size_t)z * 262144;
        ma.splus[z] = (z & 1);
    }
    ma.A[6] = Obf_mu;  ma.Wt[6] = WtB + (size_t)6 * 1048576;
    ma.bias[6] = (const float*)d_in[15]; ma.dst[6] = (float*)d_out; ma.splus[6] = 0;
    ma.A[7] = Obf_var; ma.Wt[7] = WtB + (size_t)7 * 1048576;
    ma.bias[7] = (const float*)d_in[17]; ma.dst[7] = (float*)d_out + 262144; ma.splus[7] = 1;
    ma.Abf_mu = Abf_mu; ma.Abf_var = Abf_var;
    ma.WtB = WtB; ma.Proj = Proj;
    ma.Obf_mu = Obf_mu; ma.Obf_var = Obf_var;
    ma.Gbf = Gbf; ma.cvec = cvec;

    void* kargs[] = { (void*)&ma };
    hipLaunchCooperativeKernel((void*)mega_kernel, dim3(256), dim3(256), kargs, 0, stream);
}

// Round 10
// 150.327 us; speedup vs baseline: 2.7348x; 2.7348x over previous
//
#include <hip/hip_runtime.h>
#include <math.h>

typedef __bf16 bf16_t;
typedef bf16_t bf16x4 __attribute__((ext_vector_type(4)));
typedef bf16_t bf16x8 __attribute__((ext_vector_type(8)));
typedef float  f32x4  __attribute__((ext_vector_type(4)));

__device__ __forceinline__ float softplus_f(float x) {
    return (x > 20.f) ? x : log1pf(expf(x));
}

__device__ __forceinline__ float fast_rcp(float x) {
#if __has_builtin(__builtin_amdgcn_rcpf)
    return __builtin_amdgcn_rcpf(x);
#else
    return 1.0f / x;
#endif
}

// ---------------- prep: z<8 transpose+convert weights, z==8 convert activations ----------------
struct PrepArgs { const float* src[8]; const float* mu; const float* var; };

__global__ __launch_bounds__(256) void prep_kernel(PrepArgs pa, bf16_t* __restrict__ wtbase,
                                                   bf16_t* __restrict__ dmu, bf16_t* __restrict__ dvar) {
    const int t = threadIdx.x;
    if (blockIdx.z == 8) {
        const int gid = (blockIdx.y * 16 + blockIdx.x) * 256 + t;   // 0..65535
        const float* s; bf16_t* d; int off;
        if (gid < 32768) { s = pa.mu;  d = dmu;  off = gid * 8; }
        else             { s = pa.var; d = dvar; off = (gid - 32768) * 8; }
        float4 v0 = *(const float4*)(s + off);
        float4 v1 = *(const float4*)(s + off + 4);
        bf16x8 o;
        o[0] = (bf16_t)v0.x; o[1] = (bf16_t)v0.y; o[2] = (bf16_t)v0.z; o[3] = (bf16_t)v0.w;
        o[4] = (bf16_t)v1.x; o[5] = (bf16_t)v1.y; o[6] = (bf16_t)v1.z; o[7] = (bf16_t)v1.w;
        *(bf16x8*)(d + off) = o;
        return;
    }
    const int kt = blockIdx.x, nt = blockIdx.y, wm = blockIdx.z;
    const float* __restrict__ W = pa.src[wm];
    bf16_t* __restrict__ Wt = wtbase + (size_t)wm * 1048576;
    __shared__ bf16_t Ts[64][72];
    const int r0 = t >> 4, c4 = (t & 15) * 4;
#pragma unroll
    for (int rep = 0; rep < 4; ++rep) {
        const int r = r0 + rep * 16;
        const float4 v = *(const float4*)&W[(size_t)(kt * 64 + r) * 1024 + nt * 64 + c4];
        Ts[c4 + 0][r] = (bf16_t)v.x;
        Ts[c4 + 1][r] = (bf16_t)v.y;
        Ts[c4 + 2][r] = (bf16_t)v.z;
        Ts[c4 + 3][r] = (bf16_t)v.w;
    }
    __syncthreads();
#pragma unroll
    for (int rep = 0; rep < 2; ++rep) {
        const int chunk = t + rep * 256;
        const int n = chunk >> 3, kc = (chunk & 7) * 8;
        bf16x8 v = *(const bf16x8*)&Ts[n][kc];
        *(bf16x8*)&Wt[(size_t)(nt * 64 + n) * 1024 + kt * 64 + kc] = v;
    }
}

// ---------------- gemm: 64x64 tile, intra-block split-K (R5 known-good) ----------------
struct GemmArgs {
    const bf16_t* A[6];
    const bf16_t* Wt[6];
    const float*  bias[6];
    float*        dst[6];
    int           splus[6];
};

__global__ __launch_bounds__(256, 2) void gemm_splitk(GemmArgs args) {
    const int z = blockIdx.z;
    const bf16_t* __restrict__ A    = args.A[z];
    const bf16_t* __restrict__ Wt   = args.Wt[z];
    const float*  __restrict__ bias = args.bias[z];
    float*        __restrict__ dst  = args.dst[z];
    const int sp = args.splus[z];

    const int n_base = blockIdx.x * 64;
    const int m_base = blockIdx.y * 64;

    __shared__ __align__(16) unsigned char smem_raw[73728];
    bf16_t* stage = (bf16_t*)smem_raw;
    float*  Cr    = (float*)smem_raw;

    const int t = threadIdx.x;
    const int lane = t & 63;
    const int w = t >> 6;
    bf16_t* As = stage + w * 9216;
    bf16_t* Bs = As + 4608;

    const int r8 = lane >> 3, kb = lane & 7;
    const int fr = lane & 15, fq = lane >> 4, fk = fq * 8;

    f32x4 acc[4][4] = {};

#pragma unroll
    for (int s = 0; s < 4; ++s) {
        const int k0 = w * 256 + s * 64;
#pragma unroll
        for (int i = 0; i < 8; ++i) {
            const int row = i * 8 + r8;
            bf16x8 av = *(const bf16x8*)&A [(size_t)(m_base + row) * 1024 + k0 + kb * 8];
            bf16x8 bv = *(const bf16x8*)&Wt[(size_t)(n_base + row) * 1024 + k0 + kb * 8];
            *(bf16x8*)&As[row * 72 + kb * 8] = av;
            *(bf16x8*)&Bs[row * 72 + kb * 8] = bv;
        }
#pragma unroll
        for (int kh = 0; kh < 2; ++kh) {
            bf16x8 aF[4], bF[4];
#pragma unroll
            for (int i = 0; i < 4; ++i)
                aF[i] = *(const bf16x8*)&As[(i * 16 + fr) * 72 + kh * 32 + fk];
#pragma unroll
            for (int j = 0; j < 4; ++j)
                bF[j] = *(const bf16x8*)&Bs[(j * 16 + fr) * 72 + kh * 32 + fk];
#pragma unroll
            for (int i = 0; i < 4; ++i)
#pragma unroll
                for (int j = 0; j < 4; ++j)
                    acc[i][j] = __builtin_amdgcn_mfma_f32_16x16x32_bf16(aF[i], bF[j], acc[i][j], 0, 0, 0);
        }
    }

    __syncthreads();
    {
        float* Crw = Cr + w * 4352;
        const int orow = fq * 4;
#pragma unroll
        for (int i = 0; i < 4; ++i)
#pragma unroll
            for (int j = 0; j < 4; ++j)
#pragma unroll
                for (int rr = 0; rr < 4; ++rr)
                    Crw[(i * 16 + orow + rr) * 68 + j * 16 + fr] = acc[i][j][rr];
    }
    __syncthreads();

    const int cc = (t & 15) * 4;
    f32x4 bv4 = *(const f32x4*)&bias[n_base + cc];
#pragma unroll
    for (int i = 0; i < 4; ++i) {
        const int row = (t >> 4) + i * 16;
        f32x4 s0 = *(const f32x4*)&Cr[0 * 4352 + row * 68 + cc];
        f32x4 s1 = *(const f32x4*)&Cr[1 * 4352 + row * 68 + cc];
        f32x4 s2 = *(const f32x4*)&Cr[2 * 4352 + row * 68 + cc];
        f32x4 s3 = *(const f32x4*)&Cr[3 * 4352 + row * 68 + cc];
        f32x4 v = (s0 + s1) + (s2 + s3) + bv4;
        if (sp) {
            v[0] = softplus_f(v[0]); v[1] = softplus_f(v[1]);
            v[2] = softplus_f(v[2]); v[3] = softplus_f(v[3]);
        }
        *(f32x4*)&dst[(size_t)(m_base + row) * 1024 + n_base + cc] = v;
    }
}

// ---------------- feat: Gbf[h][katt=256][d=128] bf16 (MFMA B-layout) + cvec[h][katt] ----------------
__global__ __launch_bounds__(256) void feat_kernel(const float* __restrict__ Km,
                                                   const float* __restrict__ Kv,
                                                   bf16_t* __restrict__ Gbf,
                                                   float* __restrict__ cvec) {
    const int h = blockIdx.x, kb = blockIdx.y;
    const int t = threadIdx.x;
    const int kx = t & 63;
    const int dg = t >> 6;
    const int katt = kb * 64 + kx;
    const float* kvp = Kv + (size_t)katt * 1024 + h * 64 + dg * 16;
    const float* kmp = Km + (size_t)katt * 1024 + h * 64 + dg * 16;
    bf16_t* grow = Gbf + ((size_t)(h * 256 + katt)) * 128;
    float cp = 0.f;
#pragma unroll
    for (int c = 0; c < 4; ++c) {
        f32x4 kv = *(const f32x4*)(kvp + c * 4);
        f32x4 km = *(const f32x4*)(kmp + c * 4);
        bf16x4 o1, o2;
#pragma unroll
        for (int e = 0; e < 4; ++e) {
            const float r = 0.5f * fast_rcp(kv[e]);
            o1[e] = (bf16_t)r;
            o2[e] = (bf16_t)(-2.f * km[e] * r);
            cp += km[e] * km[e] * r + 0.5f * __logf(kv[e]);
        }
        *(bf16x4*)&grow[dg * 16 + c * 4]      = o1;
        *(bf16x4*)&grow[64 + dg * 16 + c * 4] = o2;
    }
    __shared__ float red[4][64];
    red[dg][kx] = cp;
    __syncthreads();
    if (dg == 0)
        cvec[h * 256 + katt] = red[0][kx] + red[1][kx] + red[2][kx] + red[3][kx];
}

// ---------------- attn_v6: MFMA scores + MFMA PV ----------------
#define OFF_VM   0
#define OFF_VV   36864
#define OFF_FS   73728
#define OFF_SC   82176
#define OFF_PHI  98816
#define OFF_PLO  107264
#define OFF_P2H  115712
#define OFF_P2L  124160
#define ATTN_SMEM 132608

__global__ __launch_bounds__(256) void attn_v6(const float* __restrict__ Qm,
                                               const float* __restrict__ Qv,
                                               const bf16_t* __restrict__ Gbf,
                                               const float* __restrict__ cvec,
                                               const float* __restrict__ Vm,
                                               const float* __restrict__ Vv,
                                               bf16_t* __restrict__ Omu,
                                               bf16_t* __restrict__ Ovar) {
    __shared__ __align__(16) unsigned char smem[ATTN_SMEM];
    bf16_t* Vsm = (bf16_t*)(smem + OFF_VM);   // [256][72] bf16
    bf16_t* Vsv = (bf16_t*)(smem + OFF_VV);
    float*  Fs  = (float*)(smem + OFF_FS);    // [16][132] f32
    float*  Sc  = (float*)(smem + OFF_SC);    // [16][260] f32 (scaled logits)
    bf16_t* Phi = (bf16_t*)(smem + OFF_PHI);  // [16][264] bf16
    bf16_t* Plo = (bf16_t*)(smem + OFF_PLO);
    bf16_t* P2h = (bf16_t*)(smem + OFF_P2H);
    bf16_t* P2l = (bf16_t*)(smem + OFF_P2L);

    const int qt = blockIdx.x, h = blockIdx.y;
    const int t = threadIdx.x, w = t >> 6, lane = t & 63;
    const int fr = lane & 15, fq = lane >> 4;
    const int n0 = w * 64;

    const bf16_t* gB = Gbf + ((size_t)(h * 256 + n0 + fr)) * 128 + fq * 8;

    bf16x8 bcur[4];
#pragma unroll
    for (int ks = 0; ks < 4; ++ks) bcur[ks] = *(const bf16x8*)(gB + ks * 32);

    {
        const int r = t >> 4, c = t & 15;
        f32x4 qm = *(const f32x4*)(Qm + (size_t)(qt * 16 + r) * 1024 + h * 64 + c * 4);
        f32x4 qv = *(const f32x4*)(Qv + (size_t)(qt * 16 + r) * 1024 + h * 64 + c * 4);
        *(f32x4*)&Fs[r * 132 + c * 4]      = qm * qm + qv;
        *(f32x4*)&Fs[r * 132 + 64 + c * 4] = qm;
    }
    __syncthreads();

    bf16x8 ahi[4], alo[4];
#pragma unroll
    for (int ks = 0; ks < 4; ++ks) {
        f32x4 f0 = *(const f32x4*)&Fs[fr * 132 + ks * 32 + fq * 8];
        f32x4 f1 = *(const f32x4*)&Fs[fr * 132 + ks * 32 + fq * 8 + 4];
#pragma unroll
        for (int e = 0; e < 4; ++e) {
            bf16_t hb = (bf16_t)f0[e];
            ahi[ks][e] = hb; alo[ks][e] = (bf16_t)(f0[e] - (float)hb);
            bf16_t hb2 = (bf16_t)f1[e];
            ahi[ks][e + 4] = hb2; alo[ks][e + 4] = (bf16_t)(f1[e] - (float)hb2);
        }
    }

    const int vk = t >> 2, vpart = t & 3;
#pragma unroll
    for (int nt = 0; nt < 4; ++nt) {
        const int ua = 2 * nt, ub = 2 * nt + 1;
        const float* vsa = ((ua >> 2) ? Vv : Vm) + (size_t)(vk + (ua & 3) * 64) * 1024 + h * 64 + vpart * 16;
        const float* vsb = ((ub >> 2) ? Vv : Vm) + (size_t)(vk + (ub & 3) * 64) * 1024 + h * 64 + vpart * 16;
        f32x4 va0 = *(const f32x4*)(vsa),     va1 = *(const f32x4*)(vsa + 4);
        f32x4 va2 = *(const f32x4*)(vsa + 8), va3 = *(const f32x4*)(vsa + 12);
        f32x4 vb0 = *(const f32x4*)(vsb),     vb1 = *(const f32x4*)(vsb + 4);
        f32x4 vb2 = *(const f32x4*)(vsb + 8), vb3 = *(const f32x4*)(vsb + 12);

        bf16x8 bnxt[4];
        if (nt < 3) {
#pragma unroll
            for (int ks = 0; ks < 4; ++ks)
                bnxt[ks] = *(const bf16x8*)(gB + (size_t)(nt + 1) * 2048 + ks * 32);
        }

        f32x4 acc = {0.f, 0.f, 0.f, 0.f};
#pragma unroll
        for (int ks = 0; ks < 4; ++ks) {
            acc = __builtin_amdgcn_mfma_f32_16x16x32_bf16(ahi[ks], bcur[ks], acc, 0, 0, 0);
            acc = __builtin_amdgcn_mfma_f32_16x16x32_bf16(alo[ks], bcur[ks], acc, 0, 0, 0);
        }

        {
            bf16_t* da = ((ua >> 2) ? Vsv : Vsm) + (vk + (ua & 3) * 64) * 72 + vpart * 16;
            bf16_t* db = ((ub >> 2) ? Vsv : Vsm) + (vk + (ub & 3) * 64) * 72 + vpart * 16;
            bf16x8 o0, o1;
            o0[0]=(bf16_t)va0[0]; o0[1]=(bf16_t)va0[1]; o0[2]=(bf16_t)va0[2]; o0[3]=(bf16_t)va0[3];
            o0[4]=(bf16_t)va1[0]; o0[5]=(bf16_t)va1[1]; o0[6]=(bf16_t)va1[2]; o0[7]=(bf16_t)va1[3];
            o1[0]=(bf16_t)va2[0]; o1[1]=(bf16_t)va2[1]; o1[2]=(bf16_t)va2[2]; o1[3]=(bf16_t)va2[3];
            o1[4]=(bf16_t)va3[0]; o1[5]=(bf16_t)va3[1]; o1[6]=(bf16_t)va3[2]; o1[7]=(bf16_t)va3[3];
            *(bf16x8*)(da)     = o0;
            *(bf16x8*)(da + 8) = o1;
            o0[0]=(bf16_t)vb0[0]; o0[1]=(bf16_t)vb0[1]; o0[2]=(bf16_t)vb0[2]; o0[3]=(bf16_t)vb0[3];
            o0[4]=(bf16_t)vb1[0]; o0[5]=(bf16_t)vb1[1]; o0[6]=(bf16_t)vb1[2]; o0[7]=(bf16_t)vb1[3];
            o1[0]=(bf16_t)vb2[0]; o1[1]=(bf16_t)vb2[1]; o1[2]=(bf16_t)vb2[2]; o1[3]=(bf16_t)vb2[3];
            o1[4]=(bf16_t)vb3[0]; o1[5]=(bf16_t)vb3[1]; o1[6]=(bf16_t)vb3[2]; o1[7]=(bf16_t)vb3[3];
            *(bf16x8*)(db)     = o0;
            *(bf16x8*)(db + 8) = o1;
        }

        const float cv = cvec[h * 256 + n0 + nt * 16 + fr];
        f32x4 lg = (acc + cv) * (-0.125f);
#pragma unroll
        for (int reg = 0; reg < 4; ++reg)
            Sc[(fq * 4 + reg) * 260 + n0 + nt * 16 + fr] = lg[reg];

#pragma unroll
        for (int ks = 0; ks < 4; ++ks) bcur[ks] = bnxt[ks];
    }
    __syncthreads();

    const int fw = w * 4;
    f32x4 sr[4];
#pragma unroll
    for (int r = 0; r < 4; ++r)
        sr[r] = *(const f32x4*)&Sc[(fw + r) * 260 + lane * 4];
#pragma unroll
    for (int r = 0; r < 4; ++r) {
        f32x4 s = sr[r];
        float mloc = fmaxf(fmaxf(s[0], s[1]), fmaxf(s[2], s[3]));
#pragma unroll
        for (int off = 32; off > 0; off >>= 1)
            mloc = fmaxf(mloc, __shfl_xor(mloc, off, 64));
        s[0] = __expf(s[0] - mloc); s[1] = __expf(s[1] - mloc);
        s[2] = __expf(s[2] - mloc); s[3] = __expf(s[3] - mloc);
        float sl = (s[0] + s[1]) + (s[2] + s[3]);
#pragma unroll
        for (int off = 32; off > 0; off >>= 1)
            sl += __shfl_xor(sl, off, 64);
        sr[r] = s * fast_rcp(sl);
    }

#pragma unroll
    for (int r = 0; r < 4; ++r) {
        bf16x4 phi, plo, p2hi, p2lo;
#pragma unroll
        for (int e = 0; e < 4; ++e) {
            const float p = sr[r][e];
            const bf16_t hb = (bf16_t)p;
            phi[e] = hb; plo[e] = (bf16_t)(p - (float)hb);
            const float p2 = p * p;
            const bf16_t h2 = (bf16_t)p2;
            p2hi[e] = h2; p2lo[e] = (bf16_t)(p2 - (float)h2);
        }
        const int row = fw + r;
        *(bf16x4*)&Phi[row * 264 + lane * 4] = phi;
        *(bf16x4*)&Plo[row * 264 + lane * 4] = plo;
        *(bf16x4*)&P2h[row * 264 + lane * 4] = p2hi;
        *(bf16x4*)&P2l[row * 264 + lane * 4] = p2lo;
    }
    __syncthreads();

    f32x4 accm = {0.f,0.f,0.f,0.f}, accv = {0.f,0.f,0.f,0.f};
#pragma unroll
    for (int k0 = 0; k0 < 256; k0 += 32) {
        const int ka = k0 + fq * 8;
        bf16x8 ahi2 = *(const bf16x8*)&Phi[fr * 264 + ka];
        bf16x8 alo2 = *(const bf16x8*)&Plo[fr * 264 + ka];
        bf16x8 a2h  = *(const bf16x8*)&P2h[fr * 264 + ka];
        bf16x8 a2l  = *(const bf16x8*)&P2l[fr * 264 + ka];
        bf16x8 bm, bv;
#pragma unroll
        for (int j = 0; j < 8; ++j) {
            const int kk = ka + j;
            bm[j] = Vsm[kk * 72 + w * 16 + fr];
            bv[j] = Vsv[kk * 72 + w * 16 + fr];
        }
        accm = __builtin_amdgcn_mfma_f32_16x16x32_bf16(ahi2, bm, accm, 0, 0, 0);
        accm = __builtin_amdgcn_mfma_f32_16x16x32_bf16(alo2, bm, accm, 0, 0, 0);
        accv = __builtin_amdgcn_mfma_f32_16x16x32_bf16(a2h,  bv, accv, 0, 0, 0);
        accv = __builtin_amdgcn_mfma_f32_16x16x32_bf16(a2l,  bv, accv, 0, 0, 0);
    }

#pragma unroll
    for (int reg = 0; reg < 4; ++reg) {
        const int qg = qt * 16 + fq * 4 + reg;
        const size_t ob = (size_t)qg * 1024 + h * 64 + w * 16 + fr;
        Omu[ob]  = (bf16_t)accm[reg];
        Ovar[ob] = (bf16_t)accv[reg];
    }
}

// ---------------- launch ----------------
extern "C" void kernel_launch(void* const* d_in, const int* in_sizes, int n_in,
                              void* d_out, int out_size, void* d_ws, size_t ws_size,
                              hipStream_t stream) {
    const float* mu  = (const float*)d_in[0];
    const float* var = (const float*)d_in[1];

    uint8_t* ws = (uint8_t*)d_ws;
    bf16_t* Abf_mu  = (bf16_t*)(ws);                              // 512 KB
    bf16_t* Abf_var = (bf16_t*)(ws + (512u << 10));               // 512 KB
    bf16_t* WtB     = (bf16_t*)(ws + (1u << 20));                 // 8 x 2 MB
    float*  Proj    = (float*)(ws + (17u << 20));                 // 6 x 1 MB
    bf16_t* Obf_mu  = (bf16_t*)(ws + (23u << 20));                // 512 KB
    bf16_t* Obf_var = (bf16_t*)(ws + (23u << 20) + (512u << 10)); // 512 KB
    bf16_t* Gbf     = (bf16_t*)(ws + (24u << 20));                // 1 MB: [16][256][128] bf16
    float*  cvec    = (float*)(ws + (25u << 20));                 // 16 KB

    PrepArgs pa;
    for (int i = 0; i < 8; ++i) pa.src[i] = (const float*)d_in[2 + 2 * i];
    pa.mu = mu; pa.var = var;
    prep_kernel<<<dim3(16, 16, 9), 256, 0, stream>>>(pa, WtB, Abf_mu, Abf_var);

    GemmArgs g1;
    for (int z = 0; z < 6; ++z) {
        g1.A[z]    = (z & 1) ? Abf_var : Abf_mu;
        g1.Wt[z]   = WtB + (size_t)z * 1048576;
        g1.bias[z] = (const float*)d_in[3 + 2 * z];
        g1.dst[z]  = Proj + (size_t)z * 262144;
        g1.splus[z] = (z & 1);
    }
    gemm_splitk<<<dim3(16, 4, 6), 256, 0, stream>>>(g1);

    feat_kernel<<<dim3(16, 4), 256, 0, stream>>>(Proj + 2 * 262144, Proj + 3 * 262144, Gbf, cvec);

    attn_v6<<<dim3(16, 16), 256, 0, stream>>>(Proj,
                                              Proj + 262144,
                                              Gbf, cvec,
                                              Proj + 4 * 262144,
                                              Proj + 5 * 262144,
                                              Obf_mu, Obf_var);

    GemmArgs g3;
    for (int z = 0; z < 6; ++z) {
        g3.A[z]    = Obf_mu;
        g3.Wt[z]   = WtB + (size_t)6 * 1048576;
        g3.bias[z] = (const float*)d_in[15];
        g3.dst[z]  = (float*)d_out;
        g3.splus[z] = 0;
    }
    g3.A[1]    = Obf_var;
    g3.Wt[1]   = WtB + (size_t)7 * 1048576;
    g3.bias[1] = (const float*)d_in[17];
    g3.dst[1]  = (float*)d_out + 262144;
    g3.splus[1] = 1;
    gemm_splitk<<<dim3(16, 4, 2), 256, 0, stream>>>(g3);
}